// Round 21
// baseline (34.128 us; speedup 1.0000x reference)
//
#include <hip/hip_runtime.h>

// ClusteringLayer: q[n,k] = normalize_k( 1 / (1 + ||x_n - c_k||^2) )
// x: [65536,256] fp32, clusters: [256,256] fp32, out: [65536,256] fp32.
// R20 = R19/R14 champion with MFMA operands SWAPPED: mfma(bf, af) puts
// x-rows on the lane dim and cluster-cols on the reg dim, so each lane
// owns row cl with 4 consecutive cluster-cols per acc quad:
//  - stores: 16x global_store_dwordx4 per thread (was 64 scalar dwords)
//  - row-sum: in-register sum + 2 shfl_xor (was 32 shuffles)
//  - x2: no shuffles (x2full is already per-lane keyed by cl)
// Fragment contents and all staging identical to R19.

typedef float f32x4 __attribute__((ext_vector_type(4)));

#define DIM    256
#define NCLUST 256

__device__ inline int pk4_fp8(float a, float b, float c, float d) {
    int w = __builtin_amdgcn_cvt_pk_fp8_f32(a, b, 0, false);   // bytes 0,1
    w = __builtin_amdgcn_cvt_pk_fp8_f32(c, d, w, true);        // bytes 2,3
    return w;
}

// ---------------------------------------------------------------------------
// Pre-kernel: blocks 0..127 -> B' = (-2*clusters) as fp8 fragments (64 KB)
//             blocks 128..383 -> c2p1[j] = 1 + sum_d clusters[j][d]^2
// Fragment f = s*16 + t; lane l holds 8 bytes:
// B'[col = t*16 + (l&15)][k = s*32 + (l>>4)*8 + v], v = 0..7 (byte v).
// Both MFMA operand slots use the same (group,v)->k map -> permutation
// cancels regardless of operand order.
// ---------------------------------------------------------------------------
__global__ __launch_bounds__(64) void pre_kernel(const float* __restrict__ clusters,
                                                 int* __restrict__ bfrag,
                                                 float* __restrict__ c2p1) {
    int b = blockIdx.x;
    int l = threadIdx.x;
    if (b < 128) {
        int s   = b >> 4;
        int t   = b & 15;
        int col = t * 16 + (l & 15);
        int k0  = s * 32 + (l >> 4) * 8;
        const f32x4* p = reinterpret_cast<const f32x4*>(clusters + col * DIM + k0);
        f32x4 a = p[0];
        f32x4 c = p[1];
        int lo = pk4_fp8(-2.0f * a[0], -2.0f * a[1], -2.0f * a[2], -2.0f * a[3]);
        int hi = pk4_fp8(-2.0f * c[0], -2.0f * c[1], -2.0f * c[2], -2.0f * c[3]);
        bfrag[(b * 64 + l) * 2]     = lo;
        bfrag[(b * 64 + l) * 2 + 1] = hi;
    } else {
        int j = b - 128;
        const f32x4* p = reinterpret_cast<const f32x4*>(clusters + j * DIM);
        f32x4 v = p[l];
        float s = v[0] * v[0] + v[1] * v[1] + v[2] * v[2] + v[3] * v[3];
#pragma unroll
        for (int m = 32; m >= 1; m >>= 1) s += __shfl_xor(s, m, 64);
        if (l == 0) c2p1[j] = 1.0f + s;
    }
}

// ---------------------------------------------------------------------------
// Main kernel: 512 blocks x 512 threads (8 waves); 2 blocks/CU resident.
// Wave owns tile (blockIdx*8+wave): 16 rows x all 256 cols.
// acc[t] = mfma(bf, af): D rows (reg) = cluster cols, D cols (lane) = x rows.
// d = x2 + (1+c2) + acc ; q = rcp(d); row-norm = in-reg sum + 2 shuffles.
// ---------------------------------------------------------------------------
__global__ __launch_bounds__(512, 2) void cluster_kernel(const float* __restrict__ x,
                                                         const f32x4* __restrict__ bfrag,
                                                         const float* __restrict__ c2p1,
                                                         float* __restrict__ out) {
    __shared__ __align__(16) char Bs[65536];   // 64 KB fp8 fragments

    const int tid  = threadIdx.x;
    const int lane = tid & 63;
    const int wave = tid >> 6;
    const int cl   = lane & 15;
    const int g    = lane >> 4;
    const int tile = blockIdx.x * 8 + wave;

    // ---- issue this wave's X loads first (HBM; 16 x 16B per lane) ----
    f32x4 ld[16];
    {
        const float* xr = x + (size_t)(tile * 16 + cl) * DIM + g * 8;
#pragma unroll
        for (int s = 0; s < 8; ++s) {
            ld[2 * s]     = *reinterpret_cast<const f32x4*>(xr + s * 32);
            ld[2 * s + 1] = *reinterpret_cast<const f32x4*>(xr + s * 32 + 4);
        }
    }

    // ---- stage fp8 B' fragments into LDS (64 KB, L2-hot, coalesced) ----
    {
        f32x4* dst = reinterpret_cast<f32x4*>(Bs);
#pragma unroll
        for (int i = 0; i < 8; ++i) {
            int idx = i * 512 + tid;
            dst[idx] = bfrag[idx];
        }
    }
    __syncthreads();   // the only barrier (couples 8 waves)

    // ---- build fp8 A fragments + fp32 x2 (ld dies here) ----
    long af[8];
    float x2p = 0.0f;
#pragma unroll
    for (int s = 0; s < 8; ++s) {
        f32x4 a = ld[2 * s], b = ld[2 * s + 1];
        x2p += a[0]*a[0] + a[1]*a[1] + a[2]*a[2] + a[3]*a[3]
             + b[0]*b[0] + b[1]*b[1] + b[2]*b[2] + b[3]*b[3];
        unsigned lo = (unsigned)pk4_fp8(a[0], a[1], a[2], a[3]);
        unsigned hi = (unsigned)pk4_fp8(b[0], b[1], b[2], b[3]);
        af[s] = (long)(((unsigned long)hi << 32) | lo);
    }
    float x2full = x2p + __shfl_xor(x2p, 16, 64);
    x2full += __shfl_xor(x2full, 32, 64);      // x2 of row (tile*16 + cl)

    // ---- MFMA (swapped operands): clusters in A slot, x in B slot ----
    f32x4 acc[16];
#pragma unroll
    for (int t = 0; t < 16; ++t) {
        acc[t][0] = 0.f; acc[t][1] = 0.f; acc[t][2] = 0.f; acc[t][3] = 0.f;
    }
    const char* bsb = Bs + lane * 8;
    __builtin_amdgcn_s_setprio(1);
#pragma unroll
    for (int s = 0; s < 8; ++s) {
#pragma unroll
        for (int t = 0; t < 16; ++t) {
            long bf = *reinterpret_cast<const long*>(bsb + (s * 16 + t) * 512);
            acc[t] = __builtin_amdgcn_mfma_f32_16x16x32_fp8_fp8(
                bf, af[s], acc[t], 0, 0, 0);
        }
    }
    __builtin_amdgcn_s_setprio(0);

    // ---- epilogue: lane owns x-row cl; acc[t][j] = q[row cl][col t*16+g*4+j]
    float rsum = 0.0f;
#pragma unroll
    for (int t = 0; t < 16; ++t) {
        f32x4 c2q = *reinterpret_cast<const f32x4*>(&c2p1[t * 16 + g * 4]);
#pragma unroll
        for (int j = 0; j < 4; ++j) {
            float d = x2full + c2q[j] + acc[t][j];
            float q = __builtin_amdgcn_rcpf(d);
            acc[t][j] = q;
            rsum += q;
        }
    }
    // full row sum: combine the 4 g-groups holding the same row cl
    rsum += __shfl_xor(rsum, 16, 64);
    rsum += __shfl_xor(rsum, 32, 64);
    float rn = __builtin_amdgcn_rcpf(rsum);

    // ---- stores: 16 x dwordx4, row cl, cols t*16 + g*4 (+0..3) ----
    float* ob = out + (size_t)(tile * 16 + cl) * NCLUST + g * 4;
#pragma unroll
    for (int t = 0; t < 16; ++t) {
        f32x4 qv;
        qv[0] = acc[t][0] * rn; qv[1] = acc[t][1] * rn;
        qv[2] = acc[t][2] * rn; qv[3] = acc[t][3] * rn;
        *reinterpret_cast<f32x4*>(&ob[t * 16]) = qv;
    }
}

extern "C" void kernel_launch(void* const* d_in, const int* in_sizes, int n_in,
                              void* d_out, int out_size, void* d_ws, size_t ws_size,
                              hipStream_t stream) {
    const float* x        = (const float*)d_in[0];
    const float* clusters = (const float*)d_in[1];
    float* out = (float*)d_out;

    int*   bfrag = (int*)d_ws;                        // 128*64*8B = 64 KB
    float* c2p1  = (float*)((char*)d_ws + 65536);     // 1 KB

    pre_kernel<<<384, 64, 0, stream>>>(clusters, bfrag, c2p1);

    int nrows = in_sizes[0] / DIM;              // 65536
    int grid  = nrows / (8 * 16);               // 512
    cluster_kernel<<<grid, 512, 0, stream>>>(x, (const f32x4*)bfrag, c2p1, out);
}

// Round 22
// 31.351 us; speedup vs baseline: 1.0886x; 1.0886x over previous
//
#include <hip/hip_runtime.h>

// ClusteringLayer: q[n,k] = normalize_k( 1 / (1 + ||x_n - c_k||^2) )
// x: [65536,256] fp32, clusters: [256,256] fp32, out: [65536,256] fp32.
// R21 = R19 champion + phase stagger: of the two co-resident blocks per CU
// (pair (b, b+256) under round-robin dispatch), one sleeps ~3.4 us at entry
// so its load burst overlaps the partner's compute/store phase -> read and
// write streams share the memory system instead of convoying.

typedef float f32x4 __attribute__((ext_vector_type(4)));

#define DIM    256
#define NCLUST 256

__device__ inline int pk4_fp8(float a, float b, float c, float d) {
    int w = __builtin_amdgcn_cvt_pk_fp8_f32(a, b, 0, false);   // bytes 0,1
    w = __builtin_amdgcn_cvt_pk_fp8_f32(c, d, w, true);        // bytes 2,3
    return w;
}

// ---------------------------------------------------------------------------
// Pre-kernel: blocks 0..127 -> B' = (-2*clusters) as fp8 fragments (64 KB)
//             blocks 128..383 -> c2p1[j] = 1 + sum_d clusters[j][d]^2
// Fragment f = s*16 + t; lane l holds 8 bytes:
// B'[col = t*16 + (l&15)][k = s*32 + (l>>4)*8 + v], v = 0..7 (byte v).
// A uses the same (group,v)->k map, so any HW k-permutation cancels.
// ---------------------------------------------------------------------------
__global__ __launch_bounds__(64) void pre_kernel(const float* __restrict__ clusters,
                                                 int* __restrict__ bfrag,
                                                 float* __restrict__ c2p1) {
    int b = blockIdx.x;
    int l = threadIdx.x;
    if (b < 128) {
        int s   = b >> 4;
        int t   = b & 15;
        int col = t * 16 + (l & 15);
        int k0  = s * 32 + (l >> 4) * 8;
        const f32x4* p = reinterpret_cast<const f32x4*>(clusters + col * DIM + k0);
        f32x4 a = p[0];
        f32x4 c = p[1];
        int lo = pk4_fp8(-2.0f * a[0], -2.0f * a[1], -2.0f * a[2], -2.0f * a[3]);
        int hi = pk4_fp8(-2.0f * c[0], -2.0f * c[1], -2.0f * c[2], -2.0f * c[3]);
        bfrag[(b * 64 + l) * 2]     = lo;
        bfrag[(b * 64 + l) * 2 + 1] = hi;
    } else {
        int j = b - 128;
        const f32x4* p = reinterpret_cast<const f32x4*>(clusters + j * DIM);
        f32x4 v = p[l];
        float s = v[0] * v[0] + v[1] * v[1] + v[2] * v[2] + v[3] * v[3];
#pragma unroll
        for (int m = 32; m >= 1; m >>= 1) s += __shfl_xor(s, m, 64);
        if (l == 0) c2p1[j] = 1.0f + s;
    }
}

// ---------------------------------------------------------------------------
// Main kernel: 512 blocks x 512 threads (8 waves); 2 blocks/CU resident.
// Wave owns tile (blockIdx*8+wave): 16 rows x all 256 cols.
// acc = -2*x.c ; d = x2 + (1+c2) + acc ; q = rcp(d); wave-local row-norm.
// ---------------------------------------------------------------------------
__global__ __launch_bounds__(512, 2) void cluster_kernel(const float* __restrict__ x,
                                                         const f32x4* __restrict__ bfrag,
                                                         const float* __restrict__ c2p1,
                                                         float* __restrict__ out) {
    __shared__ __align__(16) char Bs[65536];   // 64 KB fp8 fragments

    const int tid  = threadIdx.x;
    const int lane = tid & 63;
    const int wave = tid >> 6;
    const int cl   = lane & 15;
    const int g    = lane >> 4;
    const int tile = blockIdx.x * 8 + wave;

    // ---- phase stagger: delay one block of each co-resident pair ~3.4 us ----
    if (blockIdx.x & 256) __builtin_amdgcn_s_sleep(127);

    // ---- issue this wave's X loads first (HBM; 16 x 16B per lane) ----
    f32x4 ld[16];
    {
        const float* xr = x + (size_t)(tile * 16 + cl) * DIM + g * 8;
#pragma unroll
        for (int s = 0; s < 8; ++s) {
            ld[2 * s]     = *reinterpret_cast<const f32x4*>(xr + s * 32);
            ld[2 * s + 1] = *reinterpret_cast<const f32x4*>(xr + s * 32 + 4);
        }
    }

    // ---- stage fp8 B' fragments into LDS (64 KB, L2-hot, coalesced) ----
    {
        f32x4* dst = reinterpret_cast<f32x4*>(Bs);
#pragma unroll
        for (int i = 0; i < 8; ++i) {
            int idx = i * 512 + tid;
            dst[idx] = bfrag[idx];
        }
    }
    __syncthreads();   // the only barrier (couples 8 waves)

    // ---- build fp8 A fragments + fp32 x2 (ld dies here) ----
    long af[8];
    float x2p = 0.0f;
#pragma unroll
    for (int s = 0; s < 8; ++s) {
        f32x4 a = ld[2 * s], b = ld[2 * s + 1];
        x2p += a[0]*a[0] + a[1]*a[1] + a[2]*a[2] + a[3]*a[3]
             + b[0]*b[0] + b[1]*b[1] + b[2]*b[2] + b[3]*b[3];
        unsigned lo = (unsigned)pk4_fp8(a[0], a[1], a[2], a[3]);
        unsigned hi = (unsigned)pk4_fp8(b[0], b[1], b[2], b[3]);
        af[s] = (long)(((unsigned long)hi << 32) | lo);
    }
    float x2full = x2p + __shfl_xor(x2p, 16, 64);
    x2full += __shfl_xor(x2full, 32, 64);      // x2 of row (tile*16 + cl)

    // ---- MFMA: 16 rows x 256 cols, fp8 B from LDS (ds_read_b64, 2-way=free) ----
    f32x4 acc[16];
#pragma unroll
    for (int t = 0; t < 16; ++t) {
        acc[t][0] = 0.f; acc[t][1] = 0.f; acc[t][2] = 0.f; acc[t][3] = 0.f;
    }
    const char* bsb = Bs + lane * 8;
    __builtin_amdgcn_s_setprio(1);
#pragma unroll
    for (int s = 0; s < 8; ++s) {
#pragma unroll
        for (int t = 0; t < 16; ++t) {
            long bf = *reinterpret_cast<const long*>(bsb + (s * 16 + t) * 512);
            acc[t] = __builtin_amdgcn_mfma_f32_16x16x32_fp8_fp8(
                af[s], bf, acc[t], 0, 0, 0);
        }
    }
    __builtin_amdgcn_s_setprio(0);

    // ---- c2p1 for this lane's columns (L2-hot; loaded late on purpose) ----
    float c2v[16];
#pragma unroll
    for (int t = 0; t < 16; ++t) c2v[t] = c2p1[t * 16 + cl];

    // ---- epilogue: d = x2 + (1+c2) + acc ; q = rcp(d); row-normalize ----
    // C/D layout: col = lane&15, row = (lane>>4)*4 + reg.
    float x2j[4];
#pragma unroll
    for (int j = 0; j < 4; ++j) x2j[j] = __shfl(x2full, g * 4 + j, 64);

    float rsum[4] = {0.f, 0.f, 0.f, 0.f};
#pragma unroll
    for (int t = 0; t < 16; ++t) {
#pragma unroll
        for (int j = 0; j < 4; ++j) {
            float d = x2j[j] + c2v[t] + acc[t][j];
            float q = __builtin_amdgcn_rcpf(d);
            acc[t][j] = q;
            rsum[j] += q;
        }
    }
#pragma unroll
    for (int j = 0; j < 4; ++j) {
        float v = rsum[j];
        v += __shfl_xor(v, 1, 64); v += __shfl_xor(v, 2, 64);
        v += __shfl_xor(v, 4, 64); v += __shfl_xor(v, 8, 64);
        rsum[j] = __builtin_amdgcn_rcpf(v);
    }
    float* ob = out + (size_t)(tile * 16) * NCLUST;
#pragma unroll
    for (int t = 0; t < 16; ++t)
#pragma unroll
        for (int j = 0; j < 4; ++j)
            ob[(g * 4 + j) * NCLUST + t * 16 + cl] = acc[t][j] * rsum[j];
}

extern "C" void kernel_launch(void* const* d_in, const int* in_sizes, int n_in,
                              void* d_out, int out_size, void* d_ws, size_t ws_size,
                              hipStream_t stream) {
    const float* x        = (const float*)d_in[0];
    const float* clusters = (const float*)d_in[1];
    float* out = (float*)d_out;

    int*   bfrag = (int*)d_ws;                        // 128*64*8B = 64 KB
    float* c2p1  = (float*)((char*)d_ws + 65536);     // 1 KB

    pre_kernel<<<384, 64, 0, stream>>>(clusters, bfrag, c2p1);

    int nrows = in_sizes[0] / DIM;              // 65536
    int grid  = nrows / (8 * 16);               // 512
    cluster_kernel<<<grid, 512, 0, stream>>>(x, (const f32x4*)bfrag, c2p1, out);
}